// Round 1
// baseline (493.210 us; speedup 1.0000x reference)
//
#include <hip/hip_runtime.h>
#include <stdint.h>
#include <stddef.h>

#define NN 4096
#define KK 1024
#define SPAN 4095u
// JAX >= 0.4.30 defaults to jax_threefry_partitionable=True (foldlike split,
// counter (0,i)). Flip to 0 for legacy threefry if absmax comes back ~0.1-3.
#define JAX_PARTITIONABLE 1

// ---------------- Threefry-2x32, 20 rounds (exact JAX algorithm) -------------
__host__ __device__ inline void tf2x32(uint32_t k0, uint32_t k1,
                                       uint32_t x0, uint32_t x1,
                                       uint32_t* o0, uint32_t* o1) {
  uint32_t ks2 = k0 ^ k1 ^ 0x1BD11BDAu;
  uint32_t v0 = x0 + k0;
  uint32_t v1 = x1 + k1;
#define TF_ROT(x, r) (((x) << (r)) | ((x) >> (32 - (r))))
#define TF_RND(r) do { v0 += v1; v1 = TF_ROT(v1, r); v1 ^= v0; } while (0)
  TF_RND(13); TF_RND(15); TF_RND(26); TF_RND(6);
  v0 += k1;  v1 += ks2 + 1u;
  TF_RND(17); TF_RND(29); TF_RND(16); TF_RND(24);
  v0 += ks2; v1 += k0 + 2u;
  TF_RND(13); TF_RND(15); TF_RND(26); TF_RND(6);
  v0 += k0;  v1 += k1 + 3u;
  TF_RND(17); TF_RND(29); TF_RND(16); TF_RND(24);
  v0 += k1;  v1 += ks2 + 4u;
  TF_RND(13); TF_RND(15); TF_RND(26); TF_RND(6);
  v0 += ks2; v1 += k0 + 5u;
#undef TF_RND
#undef TF_ROT
  *o0 = v0; *o1 = v1;
}

// jax.random.randint(key,(N,),0,N-1) element i, then off-diagonal shift.
// randint draws 2*nbits=64 random bits; offset = value64 % span, computed as
// ((hi%span) * (2^32 % span) + lo%span) % span ; 2^32 % 4095 == 256.
__device__ inline int draw_offdiag(uint32_t ka, uint32_t kb, int i) {
  uint32_t a, b;
#if JAX_PARTITIONABLE
  tf2x32(ka, kb, 0u, (uint32_t)i, &a, &b);
#else
  tf2x32(ka, kb, (uint32_t)i, (uint32_t)(NN + i), &a, &b);
#endif
  uint32_t off = ((a % SPAN) * 256u + (b % SPAN)) % SPAN;
  int j = (int)off;
  return j + ((j >= i) ? 1 : 0);
}

// Monotone order-preserving float<->uint32 encoding; 0 == "no candidate".
__device__ inline uint32_t fenc(float f) {
  uint32_t b = __float_as_uint(f);
  return (b & 0x80000000u) ? ~b : (b | 0x80000000u);
}
__device__ inline float fdec(uint32_t e) {
  uint32_t b = (e & 0x80000000u) ? (e & 0x7FFFFFFFu) : ~e;
  return __uint_as_float(b);
}

// ---------------- Kernel 1: init reduction buffers + random indices ----------
__global__ void k_init_idx(uint32_t k1a, uint32_t k1b, uint32_t k2a, uint32_t k2b,
                           uint32_t k3a, uint32_t k3b, uint32_t k4a, uint32_t k4b,
                           int* __restrict__ j1r, int* __restrict__ j1f,
                           int* __restrict__ j2r, int* __restrict__ j2f,
                           uint32_t* __restrict__ rowmax, uint32_t* __restrict__ colmax) {
  int i = blockIdx.x * blockDim.x + threadIdx.x;
  if (i >= NN) return;
  rowmax[i] = 0u;
  colmax[i] = 0u;
  j1r[i] = draw_offdiag(k1a, k1b, i);
  j1f[i] = draw_offdiag(k2a, k2b, i);
  j2r[i] = draw_offdiag(k3a, k3b, i);
  j2f[i] = draw_offdiag(k4a, k4b, i);
}

// ---------------- Kernel 2: anchors + 4 gathered imposter dot products -------
// One wave per row. anchor[k]=x_k.y_k ; irr=x_k.y_{j1r} ; irf=x_k.y_{j1f}
// icr=x_{j2r}.y_k ; icf=x_{j2f}.y_k
__global__ __launch_bounds__(256) void k_dots(
    const float* __restrict__ X, const float* __restrict__ Y,
    const int* __restrict__ j1r, const int* __restrict__ j1f,
    const int* __restrict__ j2r, const int* __restrict__ j2f,
    float* __restrict__ anchor, float* __restrict__ irr, float* __restrict__ irf,
    float* __restrict__ icr, float* __restrict__ icf) {
  int wid = threadIdx.x >> 6;
  int lane = threadIdx.x & 63;
  int row = blockIdx.x * 4 + wid;
  const float* xk = X + (size_t)row * KK;
  const float* yk = Y + (size_t)row * KK;
  const float* y1 = Y + (size_t)j1r[row] * KK;
  const float* y2 = Y + (size_t)j1f[row] * KK;
  const float* x1 = X + (size_t)j2r[row] * KK;
  const float* x2 = X + (size_t)j2f[row] * KK;
  float sa = 0.f, s1 = 0.f, s2 = 0.f, s3 = 0.f, s4 = 0.f;
  for (int t = lane; t < KK; t += 64) {
    float xv = xk[t], yv = yk[t];
    sa = fmaf(xv, yv, sa);
    s1 = fmaf(xv, y1[t], s1);
    s2 = fmaf(xv, y2[t], s2);
    s3 = fmaf(x1[t], yv, s3);
    s4 = fmaf(x2[t], yv, s4);
  }
  for (int m = 32; m >= 1; m >>= 1) {
    sa += __shfl_xor(sa, m);
    s1 += __shfl_xor(s1, m);
    s2 += __shfl_xor(s2, m);
    s3 += __shfl_xor(s3, m);
    s4 += __shfl_xor(s4, m);
  }
  if (lane == 0) {
    anchor[row] = sa; irr[row] = s1; irf[row] = s2; icr[row] = s3; icf[row] = s4;
  }
}

// ---------------- Kernel 3: fused tiled GEMM + masked row/col max ------------
#define BM 64
#define BN 64
#define BK 16
#define LDT (BM + 4)   // 68 floats: 16B-aligned rows, conflict-free strides

__global__ __launch_bounds__(256) void k_gemm_reduce(
    const float* __restrict__ X, const float* __restrict__ Y,
    const float* __restrict__ anchor,
    uint32_t* __restrict__ rowmax, uint32_t* __restrict__ colmax) {
  __shared__ float As[BK][LDT];
  __shared__ float Bs[BK][LDT];
  __shared__ uint32_t lrm[BM];
  __shared__ uint32_t lcm[BN];

  const int bi = blockIdx.y, bj = blockIdx.x;
  const int tid = threadIdx.x;
  const int tx = tid & 15, ty = tid >> 4;

  if (tid < BM) { lrm[tid] = 0u; lcm[tid] = 0u; }

  const int lrow = tid >> 2;          // 0..63
  const int lk4  = (tid & 3) * 4;     // 0,4,8,12
  const float* a_src = X + (size_t)(bi * BM + lrow) * KK + lk4;
  const float* b_src = Y + (size_t)(bj * BN + lrow) * KK + lk4;

  float acc[4][4] = {};

  for (int kk = 0; kk < KK; kk += BK) {
    float4 av = *(const float4*)(a_src + kk);
    float4 bv = *(const float4*)(b_src + kk);
    __syncthreads();
    As[lk4 + 0][lrow] = av.x; As[lk4 + 1][lrow] = av.y;
    As[lk4 + 2][lrow] = av.z; As[lk4 + 3][lrow] = av.w;
    Bs[lk4 + 0][lrow] = bv.x; Bs[lk4 + 1][lrow] = bv.y;
    Bs[lk4 + 2][lrow] = bv.z; Bs[lk4 + 3][lrow] = bv.w;
    __syncthreads();
#pragma unroll
    for (int k = 0; k < BK; ++k) {
      float4 a4 = *(const float4*)&As[k][ty * 4];
      float4 b4 = *(const float4*)&Bs[k][tx * 4];
      float a_[4] = {a4.x, a4.y, a4.z, a4.w};
      float b_[4] = {b4.x, b4.y, b4.z, b4.w};
#pragma unroll
      for (int i = 0; i < 4; ++i)
#pragma unroll
        for (int j = 0; j < 4; ++j)
          acc[i][j] = fmaf(a_[i], b_[j], acc[i][j]);
    }
  }
  __syncthreads();

  // masked reductions: strictly-below-anchor max per row and per column
  const int r0g = bi * BM + ty * 4;
  const int c0g = bj * BN + tx * 4;
  float ar[4], ac[4];
#pragma unroll
  for (int i = 0; i < 4; ++i) ar[i] = anchor[r0g + i];
#pragma unroll
  for (int j = 0; j < 4; ++j) ac[j] = anchor[c0g + j];

#pragma unroll
  for (int i = 0; i < 4; ++i) {
#pragma unroll
    for (int j = 0; j < 4; ++j) {
      float v = acc[i][j];
      int rg = r0g + i, cg = c0g + j;
      if (rg != cg) {
        if (v < ar[i]) atomicMax(&lrm[ty * 4 + i], fenc(v));
        if (v < ac[j]) atomicMax(&lcm[tx * 4 + j], fenc(v));
      }
    }
  }
  __syncthreads();
  if (tid < BM) {
    uint32_t m = lrm[tid];
    if (m) atomicMax(&rowmax[bi * BM + tid], m);
  } else if (tid < 2 * BM) {
    int t = tid - BM;
    uint32_t m = lcm[t];
    if (m) atomicMax(&colmax[bj * BN + t], m);
  }
}

// ---------------- Kernel 4: hinge terms + mean --------------------------------
__global__ __launch_bounds__(256) void k_final(
    const float* __restrict__ anchor,
    const float* __restrict__ irr, const float* __restrict__ irf,
    const float* __restrict__ icr, const float* __restrict__ icf,
    const uint32_t* __restrict__ rowmax, const uint32_t* __restrict__ colmax,
    float* __restrict__ out) {
  float s = 0.f;
  for (int k = (int)threadIdx.x; k < NN; k += 256) {
    float a = anchor[k];
    float d1 = fmaxf(irr[k] - a + 1.0f, 0.f);
    uint32_t rm = rowmax[k];
    float imp2r = rm ? fdec(rm) : irf[k];
    float d2 = fmaxf(imp2r - a + 1.0f, 0.f);
    float e1 = fmaxf(icr[k] - a + 1.0f, 0.f);
    uint32_t cm = colmax[k];
    float imp2c = cm ? fdec(cm) : icf[k];
    float e2 = fmaxf(imp2c - a + 1.0f, 0.f);
    s += d1 + d2 + e1 + e2;
  }
  __shared__ float red[4];
  for (int m = 32; m >= 1; m >>= 1) s += __shfl_xor(s, m);
  if ((threadIdx.x & 63) == 0) red[threadIdx.x >> 6] = s;
  __syncthreads();
  if (threadIdx.x == 0) out[0] = (red[0] + red[1] + red[2] + red[3]) * (1.0f / NN);
}

// -----------------------------------------------------------------------------
extern "C" void kernel_launch(void* const* d_in, const int* in_sizes, int n_in,
                              void* d_out, int out_size, void* d_ws, size_t ws_size,
                              hipStream_t stream) {
  const float* X = (const float*)d_in[0];
  const float* Y = (const float*)d_in[1];
  float* out = (float*)d_out;

  char* ws = (char*)d_ws;
  float* anchor    = (float*)(ws + 0 * 16384);
  float* irr       = (float*)(ws + 1 * 16384);
  float* irf       = (float*)(ws + 2 * 16384);
  float* icr       = (float*)(ws + 3 * 16384);
  float* icf       = (float*)(ws + 4 * 16384);
  uint32_t* rowmax = (uint32_t*)(ws + 5 * 16384);
  uint32_t* colmax = (uint32_t*)(ws + 6 * 16384);
  int* j1r         = (int*)(ws + 7 * 16384);
  int* j1f         = (int*)(ws + 8 * 16384);
  int* j2r         = (int*)(ws + 9 * 16384);
  int* j2f         = (int*)(ws + 10 * 16384);

  // subkeys = jax.random.split(jax.random.key(42), 4); key(42) == (0,42)
  uint32_t sk[4][2];
#if JAX_PARTITIONABLE
  for (int i = 0; i < 4; ++i) tf2x32(0u, 42u, 0u, (uint32_t)i, &sk[i][0], &sk[i][1]);
#else
  {
    uint32_t oa[4], ob[4];
    for (int i = 0; i < 4; ++i) tf2x32(0u, 42u, (uint32_t)i, (uint32_t)(4 + i), &oa[i], &ob[i]);
    sk[0][0] = oa[0]; sk[0][1] = oa[1];
    sk[1][0] = oa[2]; sk[1][1] = oa[3];
    sk[2][0] = ob[0]; sk[2][1] = ob[1];
    sk[3][0] = ob[2]; sk[3][1] = ob[3];
  }
#endif

  k_init_idx<<<NN / 256, 256, 0, stream>>>(
      sk[0][0], sk[0][1], sk[1][0], sk[1][1], sk[2][0], sk[2][1], sk[3][0], sk[3][1],
      j1r, j1f, j2r, j2f, rowmax, colmax);

  k_dots<<<NN / 4, 256, 0, stream>>>(X, Y, j1r, j1f, j2r, j2f,
                                     anchor, irr, irf, icr, icf);

  dim3 grid(NN / BN, NN / BM);
  k_gemm_reduce<<<grid, 256, 0, stream>>>(X, Y, anchor, rowmax, colmax);

  k_final<<<1, 256, 0, stream>>>(anchor, irr, irf, icr, icf, rowmax, colmax, out);
}

// Round 2
// 111.757 us; speedup vs baseline: 4.4132x; 4.4132x over previous
//
#include <hip/hip_runtime.h>
#include <stdint.h>
#include <stddef.h>

#define NN 4096
#define KK 1024
#define SPAN 4095u

typedef unsigned short ushort_t;
typedef __attribute__((ext_vector_type(8))) short short8v;   // 8 bf16 = 4 VGPR
typedef __attribute__((ext_vector_type(4))) float f32x4;     // MFMA C/D

// ---------------- Threefry-2x32, 20 rounds (exact JAX algorithm) -------------
__host__ __device__ inline void tf2x32(uint32_t k0, uint32_t k1,
                                       uint32_t x0, uint32_t x1,
                                       uint32_t* o0, uint32_t* o1) {
  uint32_t ks2 = k0 ^ k1 ^ 0x1BD11BDAu;
  uint32_t v0 = x0 + k0;
  uint32_t v1 = x1 + k1;
#define TF_ROT(x, r) (((x) << (r)) | ((x) >> (32 - (r))))
#define TF_RND(r) do { v0 += v1; v1 = TF_ROT(v1, r); v1 ^= v0; } while (0)
  TF_RND(13); TF_RND(15); TF_RND(26); TF_RND(6);
  v0 += k1;  v1 += ks2 + 1u;
  TF_RND(17); TF_RND(29); TF_RND(16); TF_RND(24);
  v0 += ks2; v1 += k0 + 2u;
  TF_RND(13); TF_RND(15); TF_RND(26); TF_RND(6);
  v0 += k0;  v1 += k1 + 3u;
  TF_RND(17); TF_RND(29); TF_RND(16); TF_RND(24);
  v0 += k1;  v1 += ks2 + 4u;
  TF_RND(13); TF_RND(15); TF_RND(26); TF_RND(6);
  v0 += ks2; v1 += k0 + 5u;
#undef TF_RND
#undef TF_ROT
  *o0 = v0; *o1 = v1;
}

// partitionable random_bits(key, 32, shape)[i] = bits1 ^ bits2 of tf(key,(0,i))
__device__ inline uint32_t rb32(uint32_t ka, uint32_t kb, uint32_t i) {
  uint32_t a, b;
  tf2x32(ka, kb, 0u, i, &a, &b);
  return a ^ b;
}

// Monotone order-preserving float<->uint32 encoding; 0 == "no candidate".
__device__ inline uint32_t fenc(float f) {
  uint32_t b = __float_as_uint(f);
  return (b & 0x80000000u) ? ~b : (b | 0x80000000u);
}
__device__ inline float fdec(uint32_t e) {
  uint32_t b = (e & 0x80000000u) ? (e & 0x7FFFFFFFu) : ~e;
  return __uint_as_float(b);
}

__device__ inline ushort_t bf16rne(float f) {   // fp32 -> bf16 round-nearest-even
  uint32_t u = __float_as_uint(f);
  return (ushort_t)((u + 0x7FFFu + ((u >> 16) & 1u)) >> 16);
}

// ---------------- Kernel 1: init reduction buffers + random indices ----------
// JAX semantics (threefry_partitionable=True):
//   subkey s (passed in) -> randint splits: k1=tf(sk,(0,0)), k2=tf(sk,(0,1))
//   hi_i = rb32(k1, i); lo_i = rb32(k2, i)
//   off  = ((hi%span)*(2^32%span) + lo%span) % span ; 2^32 % 4095 == 256
//   j    = off + (off >= i)
__global__ void k_init_idx(uint32_t s0a, uint32_t s0b, uint32_t s1a, uint32_t s1b,
                           uint32_t s2a, uint32_t s2b, uint32_t s3a, uint32_t s3b,
                           int* __restrict__ j1r, int* __restrict__ j1f,
                           int* __restrict__ j2r, int* __restrict__ j2f,
                           uint32_t* __restrict__ rowmax, uint32_t* __restrict__ colmax) {
  int i = blockIdx.x * blockDim.x + threadIdx.x;
  if (i >= NN) return;
  rowmax[i] = 0u;
  colmax[i] = 0u;
  uint32_t ka[4] = {s0a, s1a, s2a, s3a};
  uint32_t kb[4] = {s0b, s1b, s2b, s3b};
  int* outs[4] = {j1r, j1f, j2r, j2f};
#pragma unroll
  for (int s = 0; s < 4; ++s) {
    uint32_t k1a, k1b, k2a, k2b;
    tf2x32(ka[s], kb[s], 0u, 0u, &k1a, &k1b);
    tf2x32(ka[s], kb[s], 0u, 1u, &k2a, &k2b);
    uint32_t hi = rb32(k1a, k1b, (uint32_t)i);
    uint32_t lo = rb32(k2a, k2b, (uint32_t)i);
    uint32_t off = ((hi % SPAN) * 256u + (lo % SPAN)) % SPAN;
    int j = (int)off;
    outs[s][i] = j + ((j >= i) ? 1 : 0);
  }
}

// ---------------- Kernel 2: fp32->bf16 convert (path A staging source) -------
__global__ __launch_bounds__(256) void k_convert(const float4* __restrict__ in,
                                                 ushort4* __restrict__ out, int n4) {
  for (int i = blockIdx.x * 256 + threadIdx.x; i < n4; i += gridDim.x * 256) {
    float4 v = in[i];
    ushort4 o;
    o.x = bf16rne(v.x); o.y = bf16rne(v.y); o.z = bf16rne(v.z); o.w = bf16rne(v.w);
    out[i] = o;
  }
}

// ---------------- Kernel 3: anchors + 4 gathered imposter dot products -------
__global__ __launch_bounds__(256) void k_dots(
    const float* __restrict__ X, const float* __restrict__ Y,
    const int* __restrict__ j1r, const int* __restrict__ j1f,
    const int* __restrict__ j2r, const int* __restrict__ j2f,
    float* __restrict__ anchor, float* __restrict__ irr, float* __restrict__ irf,
    float* __restrict__ icr, float* __restrict__ icf) {
  int wid = threadIdx.x >> 6;
  int lane = threadIdx.x & 63;
  int row = blockIdx.x * 4 + wid;
  const float* xk = X + (size_t)row * KK;
  const float* yk = Y + (size_t)row * KK;
  const float* y1 = Y + (size_t)j1r[row] * KK;
  const float* y2 = Y + (size_t)j1f[row] * KK;
  const float* x1 = X + (size_t)j2r[row] * KK;
  const float* x2 = X + (size_t)j2f[row] * KK;
  float sa = 0.f, s1 = 0.f, s2 = 0.f, s3 = 0.f, s4 = 0.f;
  for (int t = lane; t < KK; t += 64) {
    float xv = xk[t], yv = yk[t];
    sa = fmaf(xv, yv, sa);
    s1 = fmaf(xv, y1[t], s1);
    s2 = fmaf(xv, y2[t], s2);
    s3 = fmaf(x1[t], yv, s3);
    s4 = fmaf(x2[t], yv, s4);
  }
  for (int m = 32; m >= 1; m >>= 1) {
    sa += __shfl_xor(sa, m);
    s1 += __shfl_xor(s1, m);
    s2 += __shfl_xor(s2, m);
    s3 += __shfl_xor(s3, m);
    s4 += __shfl_xor(s4, m);
  }
  if (lane == 0) {
    anchor[row] = sa; irr[row] = s1; irf[row] = s2; icr[row] = s3; icf[row] = s4;
  }
}

// ---------------- Kernel 4: MFMA GEMM (128x128 tile) + masked row/col max ----
#define BM 128
#define BK 32
#define NSTEP (KK / BK)

__device__ inline void glds16(const void* g, void* l) {
  __builtin_amdgcn_global_load_lds((const __attribute__((address_space(1))) void*)g,
                                   (__attribute__((address_space(3))) void*)l, 16, 0, 0);
}

template<bool GLDS>
__global__ __launch_bounds__(256) void k_mfma_reduce(
    const void* __restrict__ Ap, const void* __restrict__ Bp,
    const float* __restrict__ anchor,
    uint32_t* __restrict__ rowmax, uint32_t* __restrict__ colmax) {
  // LDS: double-buffered A,B tiles [128 rows][32 k] bf16, row-major, 16B-slot
  // XOR-swizzled: physical slot = logical slot ^ ((row>>1)&3)  (2-way banks = free)
  __shared__ ushort_t Als[2][BM * BK];
  __shared__ ushort_t Bls[2][BM * BK];

  const int tid = threadIdx.x;
  const int lane = tid & 63;
  const int w = tid >> 6, wr = w >> 1, wc = w & 1;   // 2x2 wave grid, 64x64 each
  const int l15 = lane & 15, l4 = lane >> 4;

  // XCD-aware swizzle: 1024 blocks % 8 == 0 -> simple bijective remap
  int swz = (blockIdx.x & 7) * 128 + (blockIdx.x >> 3);
  const int bi = swz >> 5, bj = swz & 31;

  const int sr = tid >> 2;   // staging row within 64-row half
  const int ss = tid & 3;    // staging 16B slot

  f32x4 acc[4][4] = {};

  const ushort_t* A16 = (const ushort_t*)Ap;
  const ushort_t* B16 = (const ushort_t*)Bp;
  const float*    A32 = (const float*)Ap;
  const float*    B32 = (const float*)Bp;

  float4 ra[4], rb[4];  // reg-staging buffers (path B)

  auto stage_g = [&](int buf, int kk) {
    int r0 = sr, r1 = 64 + sr;
    int s0 = ss ^ ((r0 >> 1) & 3), s1 = ss ^ ((r1 >> 1) & 3);
    // linear LDS dest (wave-uniform base + lane*16); swizzle applied on SOURCE
    glds16(A16 + (size_t)(bi * BM + r0) * KK + kk + s0 * 8, &Als[buf][tid * 8]);
    glds16(A16 + (size_t)(bi * BM + r1) * KK + kk + s1 * 8, &Als[buf][2048 + tid * 8]);
    glds16(B16 + (size_t)(bj * BM + r0) * KK + kk + s0 * 8, &Bls[buf][tid * 8]);
    glds16(B16 + (size_t)(bj * BM + r1) * KK + kk + s1 * 8, &Bls[buf][2048 + tid * 8]);
  };

  auto load_r = [&](int kk) {
    const float* pa0 = A32 + (size_t)(bi * BM + sr) * KK + kk + ss * 8;
    const float* pa1 = A32 + (size_t)(bi * BM + 64 + sr) * KK + kk + ss * 8;
    const float* pb0 = B32 + (size_t)(bj * BM + sr) * KK + kk + ss * 8;
    const float* pb1 = B32 + (size_t)(bj * BM + 64 + sr) * KK + kk + ss * 8;
    ra[0] = *(const float4*)pa0; ra[1] = *(const float4*)(pa0 + 4);
    ra[2] = *(const float4*)pa1; ra[3] = *(const float4*)(pa1 + 4);
    rb[0] = *(const float4*)pb0; rb[1] = *(const float4*)(pb0 + 4);
    rb[2] = *(const float4*)pb1; rb[3] = *(const float4*)(pb1 + 4);
  };

  auto commit_r = [&](int buf) {
    int r0 = sr, r1 = 64 + sr;
    int s0 = ss ^ ((r0 >> 1) & 3), s1 = ss ^ ((r1 >> 1) & 3);
    short8v p0, p1, q0, q1;
    p0[0]=bf16rne(ra[0].x); p0[1]=bf16rne(ra[0].y); p0[2]=bf16rne(ra[0].z); p0[3]=bf16rne(ra[0].w);
    p0[4]=bf16rne(ra[1].x); p0[5]=bf16rne(ra[1].y); p0[6]=bf16rne(ra[1].z); p0[7]=bf16rne(ra[1].w);
    p1[0]=bf16rne(ra[2].x); p1[1]=bf16rne(ra[2].y); p1[2]=bf16rne(ra[2].z); p1[3]=bf16rne(ra[2].w);
    p1[4]=bf16rne(ra[3].x); p1[5]=bf16rne(ra[3].y); p1[6]=bf16rne(ra[3].z); p1[7]=bf16rne(ra[3].w);
    q0[0]=bf16rne(rb[0].x); q0[1]=bf16rne(rb[0].y); q0[2]=bf16rne(rb[0].z); q0[3]=bf16rne(rb[0].w);
    q0[4]=bf16rne(rb[1].x); q0[5]=bf16rne(rb[1].y); q0[6]=bf16rne(rb[1].z); q0[7]=bf16rne(rb[1].w);
    q1[0]=bf16rne(rb[2].x); q1[1]=bf16rne(rb[2].y); q1[2]=bf16rne(rb[2].z); q1[3]=bf16rne(rb[2].w);
    q1[4]=bf16rne(rb[3].x); q1[5]=bf16rne(rb[3].y); q1[6]=bf16rne(rb[3].z); q1[7]=bf16rne(rb[3].w);
    *(short8v*)&Als[buf][r0 * 32 + s0 * 8] = p0;
    *(short8v*)&Als[buf][r1 * 32 + s1 * 8] = p1;
    *(short8v*)&Bls[buf][r0 * 32 + s0 * 8] = q0;
    *(short8v*)&Bls[buf][r1 * 32 + s1 * 8] = q1;
  };

  auto compute = [&](int buf) {
    short8v af[4], bfv[4];
#pragma unroll
    for (int m = 0; m < 4; ++m) {
      int row = wr * 64 + m * 16 + l15;
      af[m] = *(const short8v*)&Als[buf][row * 32 + (l4 ^ ((row >> 1) & 3)) * 8];
    }
#pragma unroll
    for (int n = 0; n < 4; ++n) {
      int row = wc * 64 + n * 16 + l15;
      bfv[n] = *(const short8v*)&Bls[buf][row * 32 + (l4 ^ ((row >> 1) & 3)) * 8];
    }
#pragma unroll
    for (int m = 0; m < 4; ++m)
#pragma unroll
      for (int n = 0; n < 4; ++n)
        acc[m][n] = __builtin_amdgcn_mfma_f32_16x16x32_bf16(af[m], bfv[n], acc[m][n], 0, 0, 0);
  };

  if (GLDS) {
    stage_g(0, 0);
    __syncthreads();
    int p = 0;
    for (int t = 0; t < NSTEP; ++t) {
      if (t + 1 < NSTEP) stage_g(p ^ 1, (t + 1) * BK);  // loads fly across MFMA phase
      compute(p);
      __syncthreads();                                   // vmcnt(0)+barrier
      p ^= 1;
    }
  } else {
    load_r(0); commit_r(0);
    __syncthreads();
    int p = 0;
    for (int t = 0; t < NSTEP; ++t) {
      bool more = (t + 1 < NSTEP);
      if (more) load_r((t + 1) * BK);   // T14: issue early, HBM latency under MFMA
      compute(p);
      if (more) commit_r(p ^ 1);
      __syncthreads();
      p ^= 1;
    }
  }

  // ---- epilogue: masked (strictly below anchor, off-diagonal) row/col max ----
  // C/D layout: col = lane&15, row = (lane>>4)*4 + reg   [guide §3, m89-verified]
  const int rbase = bi * BM + wr * 64;
  const int cbase = bj * BM + wc * 64;

  float ar[16], ac[4];
#pragma unroll
  for (int m = 0; m < 4; ++m)
#pragma unroll
    for (int r = 0; r < 4; ++r)
      ar[m * 4 + r] = anchor[rbase + m * 16 + l4 * 4 + r];
#pragma unroll
  for (int n = 0; n < 4; ++n)
    ac[n] = anchor[cbase + n * 16 + l15];

  // row maxima: same row across lanes sharing l4 -> reduce over l15 (xor 1,2,4,8)
#pragma unroll
  for (int m = 0; m < 4; ++m) {
#pragma unroll
    for (int r = 0; r < 4; ++r) {
      int rg = rbase + m * 16 + l4 * 4 + r;
      float a = ar[m * 4 + r];
      uint32_t e = 0;
#pragma unroll
      for (int n = 0; n < 4; ++n) {
        int cg = cbase + n * 16 + l15;
        float v = acc[m][n][r];
        if (v < a && rg != cg) { uint32_t fe = fenc(v); e = (fe > e) ? fe : e; }
      }
#pragma unroll
      for (int sh = 1; sh < 16; sh <<= 1) {
        uint32_t o = (uint32_t)__shfl_xor((int)e, sh, 64);
        e = (o > e) ? o : e;
      }
      if (l15 == 0 && e) atomicMax(&rowmax[rg], e);
    }
  }
  // col maxima: same col across lanes sharing l15 -> reduce over l4 (xor 16,32)
#pragma unroll
  for (int n = 0; n < 4; ++n) {
    int cg = cbase + n * 16 + l15;
    float a = ac[n];
    uint32_t e = 0;
#pragma unroll
    for (int m = 0; m < 4; ++m) {
#pragma unroll
      for (int r = 0; r < 4; ++r) {
        int rg = rbase + m * 16 + l4 * 4 + r;
        float v = acc[m][n][r];
        if (v < a && rg != cg) { uint32_t fe = fenc(v); e = (fe > e) ? fe : e; }
      }
    }
    {
      uint32_t o = (uint32_t)__shfl_xor((int)e, 16, 64); e = (o > e) ? o : e;
      o = (uint32_t)__shfl_xor((int)e, 32, 64);          e = (o > e) ? o : e;
    }
    if (l4 == 0 && e) atomicMax(&colmax[cg], e);
  }
}

// ---------------- Kernel 5: hinge terms + mean -------------------------------
__global__ __launch_bounds__(256) void k_final(
    const float* __restrict__ anchor,
    const float* __restrict__ irr, const float* __restrict__ irf,
    const float* __restrict__ icr, const float* __restrict__ icf,
    const uint32_t* __restrict__ rowmax, const uint32_t* __restrict__ colmax,
    float* __restrict__ out) {
  float s = 0.f;
  for (int k = (int)threadIdx.x; k < NN; k += 256) {
    float a = anchor[k];
    float d1 = fmaxf(irr[k] - a + 1.0f, 0.f);
    uint32_t rm = rowmax[k];
    float imp2r = rm ? fdec(rm) : irf[k];
    float d2 = fmaxf(imp2r - a + 1.0f, 0.f);
    float e1 = fmaxf(icr[k] - a + 1.0f, 0.f);
    uint32_t cm = colmax[k];
    float imp2c = cm ? fdec(cm) : icf[k];
    float e2 = fmaxf(imp2c - a + 1.0f, 0.f);
    s += d1 + d2 + e1 + e2;
  }
  __shared__ float red[4];
  for (int m = 32; m >= 1; m >>= 1) s += __shfl_xor(s, m);
  if ((threadIdx.x & 63) == 0) red[threadIdx.x >> 6] = s;
  __syncthreads();
  if (threadIdx.x == 0) out[0] = (red[0] + red[1] + red[2] + red[3]) * (1.0f / NN);
}

// -----------------------------------------------------------------------------
extern "C" void kernel_launch(void* const* d_in, const int* in_sizes, int n_in,
                              void* d_out, int out_size, void* d_ws, size_t ws_size,
                              hipStream_t stream) {
  const float* X = (const float*)d_in[0];
  const float* Y = (const float*)d_in[1];
  float* out = (float*)d_out;

  char* ws = (char*)d_ws;
  float* anchor    = (float*)(ws + 0 * 16384);
  float* irr       = (float*)(ws + 1 * 16384);
  float* irf       = (float*)(ws + 2 * 16384);
  float* icr       = (float*)(ws + 3 * 16384);
  float* icf       = (float*)(ws + 4 * 16384);
  uint32_t* rowmax = (uint32_t*)(ws + 5 * 16384);
  uint32_t* colmax = (uint32_t*)(ws + 6 * 16384);
  int* j1r         = (int*)(ws + 7 * 16384);
  int* j1f         = (int*)(ws + 8 * 16384);
  int* j2r         = (int*)(ws + 9 * 16384);
  int* j2f         = (int*)(ws + 10 * 16384);
  ushort_t* Xb     = (ushort_t*)(ws + 256 * 1024);
  ushort_t* Yb     = Xb + (size_t)NN * KK;

  const size_t need = 256 * 1024 + 2ull * NN * KK * sizeof(ushort_t) + 1024;
  const bool glds_ok = ws_size >= need;

  // subkeys = split(key(42), 4), partitionable: sk_i = threefry((0,42),(0,i))
  uint32_t sk[4][2];
  for (int i = 0; i < 4; ++i) tf2x32(0u, 42u, 0u, (uint32_t)i, &sk[i][0], &sk[i][1]);

  k_init_idx<<<NN / 256, 256, 0, stream>>>(
      sk[0][0], sk[0][1], sk[1][0], sk[1][1], sk[2][0], sk[2][1], sk[3][0], sk[3][1],
      j1r, j1f, j2r, j2f, rowmax, colmax);

  k_dots<<<NN / 4, 256, 0, stream>>>(X, Y, j1r, j1f, j2r, j2f,
                                     anchor, irr, irf, icr, icf);

  if (glds_ok) {
    const int n4 = NN * KK / 4;
    k_convert<<<2048, 256, 0, stream>>>((const float4*)X, (ushort4*)Xb, n4);
    k_convert<<<2048, 256, 0, stream>>>((const float4*)Y, (ushort4*)Yb, n4);
    k_mfma_reduce<true><<<1024, 256, 0, stream>>>(Xb, Yb, anchor, rowmax, colmax);
  } else {
    k_mfma_reduce<false><<<1024, 256, 0, stream>>>(X, Y, anchor, rowmax, colmax);
  }

  k_final<<<1, 256, 0, stream>>>(anchor, irr, irf, icr, icf, rowmax, colmax, out);
}

// Round 3
// 103.028 us; speedup vs baseline: 4.7872x; 1.0847x over previous
//
#include <hip/hip_runtime.h>
#include <stdint.h>
#include <stddef.h>

#define NN 4096
#define KK 1024
#define SPAN 4095u

typedef unsigned short ushort_t;
typedef __attribute__((ext_vector_type(8))) short short8v;   // 8 bf16 = 4 VGPR
typedef __attribute__((ext_vector_type(4))) float f32x4;     // MFMA C/D

// ---------------- Threefry-2x32, 20 rounds (exact JAX algorithm) -------------
__host__ __device__ inline void tf2x32(uint32_t k0, uint32_t k1,
                                       uint32_t x0, uint32_t x1,
                                       uint32_t* o0, uint32_t* o1) {
  uint32_t ks2 = k0 ^ k1 ^ 0x1BD11BDAu;
  uint32_t v0 = x0 + k0;
  uint32_t v1 = x1 + k1;
#define TF_ROT(x, r) (((x) << (r)) | ((x) >> (32 - (r))))
#define TF_RND(r) do { v0 += v1; v1 = TF_ROT(v1, r); v1 ^= v0; } while (0)
  TF_RND(13); TF_RND(15); TF_RND(26); TF_RND(6);
  v0 += k1;  v1 += ks2 + 1u;
  TF_RND(17); TF_RND(29); TF_RND(16); TF_RND(24);
  v0 += ks2; v1 += k0 + 2u;
  TF_RND(13); TF_RND(15); TF_RND(26); TF_RND(6);
  v0 += k0;  v1 += k1 + 3u;
  TF_RND(17); TF_RND(29); TF_RND(16); TF_RND(24);
  v0 += k1;  v1 += ks2 + 4u;
  TF_RND(13); TF_RND(15); TF_RND(26); TF_RND(6);
  v0 += ks2; v1 += k0 + 5u;
#undef TF_RND
#undef TF_ROT
  *o0 = v0; *o1 = v1;
}

// partitionable random_bits(key, 32, shape)[i] = bits1 ^ bits2 of tf(key,(0,i))
__device__ inline uint32_t rb32(uint32_t ka, uint32_t kb, uint32_t i) {
  uint32_t a, b;
  tf2x32(ka, kb, 0u, i, &a, &b);
  return a ^ b;
}

// Monotone order-preserving float<->uint32 encoding; 0 == "no candidate".
__device__ inline uint32_t fenc(float f) {
  uint32_t b = __float_as_uint(f);
  return (b & 0x80000000u) ? ~b : (b | 0x80000000u);
}
__device__ inline float fdec(uint32_t e) {
  uint32_t b = (e & 0x80000000u) ? (e & 0x7FFFFFFFu) : ~e;
  return __uint_as_float(b);
}

__device__ inline ushort_t bf16rne(float f) {   // fp32 -> bf16 round-nearest-even
  uint32_t u = __float_as_uint(f);
  return (ushort_t)((u + 0x7FFFu + ((u >> 16) & 1u)) >> 16);
}

__device__ inline void glds16(const void* g, void* l) {
  __builtin_amdgcn_global_load_lds((const __attribute__((address_space(1))) void*)g,
                                   (__attribute__((address_space(3))) void*)l, 16, 0, 0);
}

template <int N> __device__ __forceinline__ void vmwait() {
  if constexpr (N == 8)      asm volatile("s_waitcnt vmcnt(8)" ::: "memory");
  else if constexpr (N == 4) asm volatile("s_waitcnt vmcnt(4)" ::: "memory");
  else                       asm volatile("s_waitcnt vmcnt(0)" ::: "memory");
}

// ---------------- Kernel 1: fp32->bf16 convert for X,Y + zero max tables -----
__global__ __launch_bounds__(256) void k_prep(
    const float4* __restrict__ X, const float4* __restrict__ Y,
    ushort4* __restrict__ Xb, ushort4* __restrict__ Yb,
    uint32_t* __restrict__ rowmax, uint32_t* __restrict__ colmax) {
  const int b = blockIdx.x, tid = threadIdx.x;
  if (b < 16) rowmax[b * 256 + tid] = 0u;
  else if (b < 32) colmax[(b - 16) * 256 + tid] = 0u;
  const float4* src = (b < 2048) ? X : Y;
  ushort4* dst = (b < 2048) ? Xb : Yb;
  const int n4 = NN * KK / 4;
  for (int i = (b & 2047) * 256 + tid; i < n4; i += 2048 * 256) {
    float4 v = src[i];
    ushort4 o;
    o.x = bf16rne(v.x); o.y = bf16rne(v.y); o.z = bf16rne(v.z); o.w = bf16rne(v.w);
    dst[i] = o;
  }
}

// ---------------- Kernel 2: anchors + 4 gathered imposter dots (inline PRNG) -
__global__ __launch_bounds__(256) void k_dots(
    const float* __restrict__ X, const float* __restrict__ Y,
    uint32_t s0a, uint32_t s0b, uint32_t s1a, uint32_t s1b,
    uint32_t s2a, uint32_t s2b, uint32_t s3a, uint32_t s3b,
    float* __restrict__ anchor, float* __restrict__ irr, float* __restrict__ irf,
    float* __restrict__ icr, float* __restrict__ icf) {
  const int wid = threadIdx.x >> 6;
  const int lane = threadIdx.x & 63;
  const int row = blockIdx.x * 4 + wid;

  // lanes 0..3 each draw one off-diagonal index (randint: split key, 2x32 bits)
  int jl = 0;
  if (lane < 4) {
    uint32_t ka = (lane == 0) ? s0a : (lane == 1) ? s1a : (lane == 2) ? s2a : s3a;
    uint32_t kb = (lane == 0) ? s0b : (lane == 1) ? s1b : (lane == 2) ? s2b : s3b;
    uint32_t k1a, k1b, k2a, k2b;
    tf2x32(ka, kb, 0u, 0u, &k1a, &k1b);
    tf2x32(ka, kb, 0u, 1u, &k2a, &k2b);
    uint32_t hi = rb32(k1a, k1b, (uint32_t)row);
    uint32_t lo = rb32(k2a, k2b, (uint32_t)row);
    uint32_t off = ((hi % SPAN) * 256u + (lo % SPAN)) % SPAN;
    int j = (int)off;
    jl = j + ((j >= row) ? 1 : 0);
  }
  const int j1r = __shfl(jl, 0), j1f = __shfl(jl, 1);
  const int j2r = __shfl(jl, 2), j2f = __shfl(jl, 3);

  const float4* xk = (const float4*)(X + (size_t)row * KK);
  const float4* yk = (const float4*)(Y + (size_t)row * KK);
  const float4* y1 = (const float4*)(Y + (size_t)j1r * KK);
  const float4* y2 = (const float4*)(Y + (size_t)j1f * KK);
  const float4* x1 = (const float4*)(X + (size_t)j2r * KK);
  const float4* x2 = (const float4*)(X + (size_t)j2f * KK);
  float sa = 0.f, s1 = 0.f, s2 = 0.f, s3 = 0.f, s4 = 0.f;
  for (int t = lane; t < KK / 4; t += 64) {
    float4 xv = xk[t], yv = yk[t], a1 = y1[t], a2 = y2[t], b1 = x1[t], b2 = x2[t];
    sa = fmaf(xv.x, yv.x, fmaf(xv.y, yv.y, fmaf(xv.z, yv.z, fmaf(xv.w, yv.w, sa))));
    s1 = fmaf(xv.x, a1.x, fmaf(xv.y, a1.y, fmaf(xv.z, a1.z, fmaf(xv.w, a1.w, s1))));
    s2 = fmaf(xv.x, a2.x, fmaf(xv.y, a2.y, fmaf(xv.z, a2.z, fmaf(xv.w, a2.w, s2))));
    s3 = fmaf(b1.x, yv.x, fmaf(b1.y, yv.y, fmaf(b1.z, yv.z, fmaf(b1.w, yv.w, s3))));
    s4 = fmaf(b2.x, yv.x, fmaf(b2.y, yv.y, fmaf(b2.z, yv.z, fmaf(b2.w, yv.w, s4))));
  }
  for (int m = 32; m >= 1; m >>= 1) {
    sa += __shfl_xor(sa, m);
    s1 += __shfl_xor(s1, m);
    s2 += __shfl_xor(s2, m);
    s3 += __shfl_xor(s3, m);
    s4 += __shfl_xor(s4, m);
  }
  if (lane == 0) {
    anchor[row] = sa; irr[row] = s1; irf[row] = s2; icr[row] = s3; icf[row] = s4;
  }
}

// ---------------- Kernel 3: 256x256 MFMA GEMM, 4-deep pipeline, counted vmcnt
#define TBM 256
#define TBK 32
#define TNT (KK / TBK)   // 32 K-tiles
// LDS: 4 circular slots x (A 16KB + B 16KB) = 128 KB. 16B-slot XOR swizzle
// (phys = log ^ ((row>>1)&3)) applied on global SOURCE + on ds_read (rule #21);
// measured 0 bank conflicts with this scheme in round 2.

__global__ __launch_bounds__(512, 2) void k_gemm256(
    const ushort_t* __restrict__ A, const ushort_t* __restrict__ B,
    const float* __restrict__ anchor,
    uint32_t* __restrict__ rowmax, uint32_t* __restrict__ colmax) {
  __shared__ ushort_t Als[4][TBM * TBK];
  __shared__ ushort_t Bls[4][TBM * TBK];

  const int tid = threadIdx.x;
  const int lane = tid & 63;
  const int w = tid >> 6;               // 8 waves: 2M x 4N
  const int wr = w >> 2, wc = w & 3;    // per-wave C: 128 x 64
  const int l15 = lane & 15, l4 = lane >> 4;

  // T1: XCD-aware bijective swizzle (256 blocks % 8 == 0)
  const int swz = (blockIdx.x & 7) * 32 + (blockIdx.x >> 3);
  const int bi = swz >> 4, bj = swz & 15;

  // staging: 512 threads x 16B covers 128 rows x 32k; two issues per matrix
  const int sr = tid >> 2;                   // 0..127
  const int ps = (tid & 3) ^ ((sr >> 1) & 3);   // same for row sr and sr+128
  const ushort_t* Ab0 = A + (size_t)(bi * TBM + sr) * KK + ps * 8;
  const ushort_t* Ab1 = Ab0 + (size_t)128 * KK;
  const ushort_t* Bb0 = B + (size_t)(bj * TBM + sr) * KK + ps * 8;
  const ushort_t* Bb1 = Bb0 + (size_t)128 * KK;

  // fragment ds_read offsets (loop-invariant, in ushort units)
  int aoff[8], boff[4];
#pragma unroll
  for (int m = 0; m < 8; ++m) {
    int row = wr * 128 + m * 16 + l15;
    aoff[m] = row * TBK + ((l4 ^ ((row >> 1) & 3)) * 8);
  }
#pragma unroll
  for (int n = 0; n < 4; ++n) {
    int row = wc * 64 + n * 16 + l15;
    boff[n] = row * TBK + ((l4 ^ ((row >> 1) & 3)) * 8);
  }

  f32x4 acc[8][4] = {};

#define STAGE(SLOT, KKOFF)                                   \
  do {                                                       \
    glds16(Ab0 + (KKOFF), &Als[SLOT][tid * 8]);              \
    glds16(Ab1 + (KKOFF), &Als[SLOT][4096 + tid * 8]);       \
    glds16(Bb0 + (KKOFF), &Bls[SLOT][tid * 8]);              \
    glds16(Bb1 + (KKOFF), &Bls[SLOT][4096 + tid * 8]);       \
  } while (0)

#define GITER(T, VMN, DOSTAGE)                               \
  do {                                                       \
    vmwait<VMN>();                                           \
    __builtin_amdgcn_s_barrier();                            \
    asm volatile("" ::: "memory");                           \
    const int slot_ = (T) & 3;                               \
    if (DOSTAGE) STAGE(((T) + 3) & 3, ((T) + 3) * TBK);      \
    short8v bf[4];                                           \
    _Pragma("unroll")                                        \
    for (int n = 0; n < 4; ++n)                              \
      bf[n] = *(const short8v*)&Bls[slot_][boff[n]];         \
    __builtin_amdgcn_s_setprio(1);                           \
    _Pragma("unroll")                                        \
    for (int m = 0; m < 8; ++m) {                            \
      short8v am = *(const short8v*)&Als[slot_][aoff[m]];    \
      _Pragma("unroll")                                      \
      for (int n = 0; n < 4; ++n)                            \
        acc[m][n] = __builtin_amdgcn_mfma_f32_16x16x32_bf16( \
            am, bf[n], acc[m][n], 0, 0, 0);                  \
    }                                                        \
    __builtin_amdgcn_s_setprio(0);                           \
  } while (0)

  // prologue: 3 tiles in flight (12 loads)
  STAGE(0, 0);
  STAGE(1, TBK);
  STAGE(2, 2 * TBK);

  for (int t = 0; t < TNT - 3; ++t) GITER(t, 8, true);   // steady: vmcnt(8)
  GITER(TNT - 3, 8, false);
  GITER(TNT - 2, 4, false);
  GITER(TNT - 1, 0, false);

#undef GITER
#undef STAGE

  // ---- epilogue: masked (strictly below anchor, off-diagonal) row/col max ----
  // C/D layout: col = lane&15, row = (lane>>4)*4 + reg
  const int rbase = bi * TBM + wr * 128;
  const int cbase = bj * TBM + wc * 64;

  float ar[32], ac[4];
#pragma unroll
  for (int m = 0; m < 8; ++m)
#pragma unroll
    for (int r = 0; r < 4; ++r)
      ar[m * 4 + r] = anchor[rbase + m * 16 + l4 * 4 + r];
#pragma unroll
  for (int n = 0; n < 4; ++n)
    ac[n] = anchor[cbase + n * 16 + l15];

  // row maxima: reduce over l15 (xor 1,2,4,8)
#pragma unroll
  for (int m = 0; m < 8; ++m) {
#pragma unroll
    for (int r = 0; r < 4; ++r) {
      const int rg = rbase + m * 16 + l4 * 4 + r;
      const float a = ar[m * 4 + r];
      uint32_t e = 0;
#pragma unroll
      for (int n = 0; n < 4; ++n) {
        const int cg = cbase + n * 16 + l15;
        float v = acc[m][n][r];
        if (v < a && rg != cg) { uint32_t fe = fenc(v); e = (fe > e) ? fe : e; }
      }
#pragma unroll
      for (int sh = 1; sh < 16; sh <<= 1) {
        uint32_t o = (uint32_t)__shfl_xor((int)e, sh, 64);
        e = (o > e) ? o : e;
      }
      if (l15 == 0 && e) atomicMax(&rowmax[rg], e);
    }
  }
  // col maxima: reduce over l4 (xor 16,32)
#pragma unroll
  for (int n = 0; n < 4; ++n) {
    const int cg = cbase + n * 16 + l15;
    const float a = ac[n];
    uint32_t e = 0;
#pragma unroll
    for (int m = 0; m < 8; ++m) {
#pragma unroll
      for (int r = 0; r < 4; ++r) {
        const int rg = rbase + m * 16 + l4 * 4 + r;
        float v = acc[m][n][r];
        if (v < a && rg != cg) { uint32_t fe = fenc(v); e = (fe > e) ? fe : e; }
      }
    }
    {
      uint32_t o = (uint32_t)__shfl_xor((int)e, 16, 64); e = (o > e) ? o : e;
      o = (uint32_t)__shfl_xor((int)e, 32, 64);          e = (o > e) ? o : e;
    }
    if (l4 == 0 && e) atomicMax(&colmax[cg], e);
  }
}

// ---------------- Kernel 4: hinge terms + mean -------------------------------
__global__ __launch_bounds__(256) void k_final(
    const float* __restrict__ anchor,
    const float* __restrict__ irr, const float* __restrict__ irf,
    const float* __restrict__ icr, const float* __restrict__ icf,
    const uint32_t* __restrict__ rowmax, const uint32_t* __restrict__ colmax,
    float* __restrict__ out) {
  float s = 0.f;
  for (int k = (int)threadIdx.x; k < NN; k += 256) {
    float a = anchor[k];
    float d1 = fmaxf(irr[k] - a + 1.0f, 0.f);
    uint32_t rm = rowmax[k];
    float imp2r = rm ? fdec(rm) : irf[k];
    float d2 = fmaxf(imp2r - a + 1.0f, 0.f);
    float e1 = fmaxf(icr[k] - a + 1.0f, 0.f);
    uint32_t cm = colmax[k];
    float imp2c = cm ? fdec(cm) : icf[k];
    float e2 = fmaxf(imp2c - a + 1.0f, 0.f);
    s += d1 + d2 + e1 + e2;
  }
  __shared__ float red[4];
  for (int m = 32; m >= 1; m >>= 1) s += __shfl_xor(s, m);
  if ((threadIdx.x & 63) == 0) red[threadIdx.x >> 6] = s;
  __syncthreads();
  if (threadIdx.x == 0) out[0] = (red[0] + red[1] + red[2] + red[3]) * (1.0f / NN);
}

// -----------------------------------------------------------------------------
extern "C" void kernel_launch(void* const* d_in, const int* in_sizes, int n_in,
                              void* d_out, int out_size, void* d_ws, size_t ws_size,
                              hipStream_t stream) {
  const float* X = (const float*)d_in[0];
  const float* Y = (const float*)d_in[1];
  float* out = (float*)d_out;

  char* ws = (char*)d_ws;
  float* anchor    = (float*)(ws + 0 * 16384);
  float* irr       = (float*)(ws + 1 * 16384);
  float* irf       = (float*)(ws + 2 * 16384);
  float* icr       = (float*)(ws + 3 * 16384);
  float* icf       = (float*)(ws + 4 * 16384);
  uint32_t* rowmax = (uint32_t*)(ws + 5 * 16384);
  uint32_t* colmax = (uint32_t*)(ws + 6 * 16384);
  ushort_t* Xb     = (ushort_t*)(ws + 256 * 1024);
  ushort_t* Yb     = Xb + (size_t)NN * KK;

  // subkeys = split(key(42), 4), partitionable: sk_i = threefry((0,42),(0,i))
  uint32_t sk[4][2];
  for (int i = 0; i < 4; ++i) tf2x32(0u, 42u, 0u, (uint32_t)i, &sk[i][0], &sk[i][1]);

  k_prep<<<4096, 256, 0, stream>>>((const float4*)X, (const float4*)Y,
                                   (ushort4*)Xb, (ushort4*)Yb, rowmax, colmax);

  k_dots<<<NN / 4, 256, 0, stream>>>(X, Y,
      sk[0][0], sk[0][1], sk[1][0], sk[1][1], sk[2][0], sk[2][1], sk[3][0], sk[3][1],
      anchor, irr, irf, icr, icf);

  k_gemm256<<<256, 512, 0, stream>>>(Xb, Yb, anchor, rowmax, colmax);

  k_final<<<1, 256, 0, stream>>>(anchor, irr, irf, icr, icf, rowmax, colmax, out);
}

// Round 4
// 99.877 us; speedup vs baseline: 4.9382x; 1.0315x over previous
//
#include <hip/hip_runtime.h>
#include <stdint.h>
#include <stddef.h>

#define NN 4096
#define KK 1024
#define SPAN 4095u

typedef unsigned short ushort_t;
typedef __attribute__((ext_vector_type(8))) short short8v;   // 8 bf16 = 4 VGPR
typedef __attribute__((ext_vector_type(4))) float f32x4;     // MFMA C/D

// ---------------- Threefry-2x32, 20 rounds (exact JAX algorithm) -------------
__host__ __device__ inline void tf2x32(uint32_t k0, uint32_t k1,
                                       uint32_t x0, uint32_t x1,
                                       uint32_t* o0, uint32_t* o1) {
  uint32_t ks2 = k0 ^ k1 ^ 0x1BD11BDAu;
  uint32_t v0 = x0 + k0;
  uint32_t v1 = x1 + k1;
#define TF_ROT(x, r) (((x) << (r)) | ((x) >> (32 - (r))))
#define TF_RND(r) do { v0 += v1; v1 = TF_ROT(v1, r); v1 ^= v0; } while (0)
  TF_RND(13); TF_RND(15); TF_RND(26); TF_RND(6);
  v0 += k1;  v1 += ks2 + 1u;
  TF_RND(17); TF_RND(29); TF_RND(16); TF_RND(24);
  v0 += ks2; v1 += k0 + 2u;
  TF_RND(13); TF_RND(15); TF_RND(26); TF_RND(6);
  v0 += k0;  v1 += k1 + 3u;
  TF_RND(17); TF_RND(29); TF_RND(16); TF_RND(24);
  v0 += k1;  v1 += ks2 + 4u;
  TF_RND(13); TF_RND(15); TF_RND(26); TF_RND(6);
  v0 += ks2; v1 += k0 + 5u;
#undef TF_RND
#undef TF_ROT
  *o0 = v0; *o1 = v1;
}

// partitionable random_bits(key, 32, shape)[i] = bits1 ^ bits2 of tf(key,(0,i))
__device__ inline uint32_t rb32(uint32_t ka, uint32_t kb, uint32_t i) {
  uint32_t a, b;
  tf2x32(ka, kb, 0u, i, &a, &b);
  return a ^ b;
}

// Monotone order-preserving float<->uint32 encoding; 0 == "no candidate".
__device__ inline uint32_t fenc(float f) {
  uint32_t b = __float_as_uint(f);
  return (b & 0x80000000u) ? ~b : (b | 0x80000000u);
}
__device__ inline float fdec(uint32_t e) {
  uint32_t b = (e & 0x80000000u) ? (e & 0x7FFFFFFFu) : ~e;
  return __uint_as_float(b);
}

__device__ inline ushort_t bf16rne(float f) {   // fp32 -> bf16 round-nearest-even
  uint32_t u = __float_as_uint(f);
  return (ushort_t)((u + 0x7FFFu + ((u >> 16) & 1u)) >> 16);
}

__device__ inline void glds16(const void* g, void* l) {
  __builtin_amdgcn_global_load_lds((const __attribute__((address_space(1))) void*)g,
                                   (__attribute__((address_space(3))) void*)l, 16, 0, 0);
}

// ---------------- Kernel 1: fp32->bf16 convert for X,Y + zero max tables -----
__global__ __launch_bounds__(256) void k_prep(
    const float4* __restrict__ X, const float4* __restrict__ Y,
    ushort4* __restrict__ Xb, ushort4* __restrict__ Yb,
    uint32_t* __restrict__ rowmax, uint32_t* __restrict__ colmax) {
  const int b = blockIdx.x, tid = threadIdx.x;
  if (b < 16) rowmax[b * 256 + tid] = 0u;
  else if (b < 32) colmax[(b - 16) * 256 + tid] = 0u;
  const float4* src = (b < 2048) ? X : Y;
  ushort4* dst = (b < 2048) ? Xb : Yb;
  const int n4 = NN * KK / 4;
  for (int i = (b & 2047) * 256 + tid; i < n4; i += 2048 * 256) {
    float4 v = src[i];
    ushort4 o;
    o.x = bf16rne(v.x); o.y = bf16rne(v.y); o.z = bf16rne(v.z); o.w = bf16rne(v.w);
    dst[i] = o;
  }
}

// ---------------- Kernel 2: anchors + 4 gathered imposter dots (inline PRNG) -
__global__ __launch_bounds__(256) void k_dots(
    const float* __restrict__ X, const float* __restrict__ Y,
    uint32_t s0a, uint32_t s0b, uint32_t s1a, uint32_t s1b,
    uint32_t s2a, uint32_t s2b, uint32_t s3a, uint32_t s3b,
    float* __restrict__ anchor, float* __restrict__ irr, float* __restrict__ irf,
    float* __restrict__ icr, float* __restrict__ icf) {
  const int wid = threadIdx.x >> 6;
  const int lane = threadIdx.x & 63;
  const int row = blockIdx.x * 4 + wid;

  int jl = 0;
  if (lane < 4) {
    uint32_t ka = (lane == 0) ? s0a : (lane == 1) ? s1a : (lane == 2) ? s2a : s3a;
    uint32_t kb = (lane == 0) ? s0b : (lane == 1) ? s1b : (lane == 2) ? s2b : s3b;
    uint32_t k1a, k1b, k2a, k2b;
    tf2x32(ka, kb, 0u, 0u, &k1a, &k1b);
    tf2x32(ka, kb, 0u, 1u, &k2a, &k2b);
    uint32_t hi = rb32(k1a, k1b, (uint32_t)row);
    uint32_t lo = rb32(k2a, k2b, (uint32_t)row);
    uint32_t off = ((hi % SPAN) * 256u + (lo % SPAN)) % SPAN;
    int j = (int)off;
    jl = j + ((j >= row) ? 1 : 0);
  }
  const int j1r = __shfl(jl, 0), j1f = __shfl(jl, 1);
  const int j2r = __shfl(jl, 2), j2f = __shfl(jl, 3);

  const float4* xk = (const float4*)(X + (size_t)row * KK);
  const float4* yk = (const float4*)(Y + (size_t)row * KK);
  const float4* y1 = (const float4*)(Y + (size_t)j1r * KK);
  const float4* y2 = (const float4*)(Y + (size_t)j1f * KK);
  const float4* x1 = (const float4*)(X + (size_t)j2r * KK);
  const float4* x2 = (const float4*)(X + (size_t)j2f * KK);
  float sa = 0.f, s1 = 0.f, s2 = 0.f, s3 = 0.f, s4 = 0.f;
  for (int t = lane; t < KK / 4; t += 64) {
    float4 xv = xk[t], yv = yk[t], a1 = y1[t], a2 = y2[t], b1 = x1[t], b2 = x2[t];
    sa = fmaf(xv.x, yv.x, fmaf(xv.y, yv.y, fmaf(xv.z, yv.z, fmaf(xv.w, yv.w, sa))));
    s1 = fmaf(xv.x, a1.x, fmaf(xv.y, a1.y, fmaf(xv.z, a1.z, fmaf(xv.w, a1.w, s1))));
    s2 = fmaf(xv.x, a2.x, fmaf(xv.y, a2.y, fmaf(xv.z, a2.z, fmaf(xv.w, a2.w, s2))));
    s3 = fmaf(b1.x, yv.x, fmaf(b1.y, yv.y, fmaf(b1.z, yv.z, fmaf(b1.w, yv.w, s3))));
    s4 = fmaf(b2.x, yv.x, fmaf(b2.y, yv.y, fmaf(b2.z, yv.z, fmaf(b2.w, yv.w, s4))));
  }
  for (int m = 32; m >= 1; m >>= 1) {
    sa += __shfl_xor(sa, m);
    s1 += __shfl_xor(s1, m);
    s2 += __shfl_xor(s2, m);
    s3 += __shfl_xor(s3, m);
    s4 += __shfl_xor(s4, m);
  }
  if (lane == 0) {
    anchor[row] = sa; irr[row] = s1; irf[row] = s2; icr[row] = s3; icf[row] = s4;
  }
}

// ---------------- Kernel 3: 256x256 MFMA GEMM, BK=64, dbuf, 4 phases/tile ----
// LDS per buf: A[256][64] + B[256][64] bf16 = 64 KB; 2 bufs = 128 KB.
// Bank layout: 128 B/row => every row starts at bank 0; conflict-free via
// phys_16B_slot = logical_slot ^ (row & 7)  (8 distinct bank-quads per
// 8-lane phase group; 2-way aliasing only = free). Applied on global SOURCE
// (linear LDS dest, rule #21) and on ds_read address.
// Stage of tile t+1 goes to buf^1 (never aliases reads) and is fully issued
// in phases 0-1, so the per-tile __syncthreads vmcnt(0) drain is covered by
// ~2300 cyc of compute >> ~900 cyc HBM latency.

__global__ __launch_bounds__(512, 2) void k_gemm256(
    const ushort_t* __restrict__ A, const ushort_t* __restrict__ B,
    const float* __restrict__ anchor,
    uint32_t* __restrict__ rowmax, uint32_t* __restrict__ colmax) {
  __shared__ ushort_t AL[2][256 * 64];
  __shared__ ushort_t BL[2][256 * 64];

  const int tid = threadIdx.x;
  const int lane = tid & 63;
  const int w = tid >> 6, wr = w >> 2, wc = w & 3;   // 8 waves: 2M x 4N
  const int l15 = lane & 15, l4 = lane >> 4;

  // T1: XCD-aware bijective swizzle (256 blocks, 256 % 8 == 0)
  const int swz = (blockIdx.x & 7) * 32 + (blockIdx.x >> 3);
  const int bi = swz >> 4, bj = swz & 15;

  // staging map: thread -> (row = tid>>3 (+64*i), phys slot = tid&7)
  // global k-slot = phys ^ (row&7); (row+64i)&7 == row&7, so one constant.
  const int strow = tid >> 3;
  const int scol = ((tid & 7) ^ (strow & 7)) * 8;
  const ushort_t* Asrc = A + (size_t)(bi * 256 + strow) * KK + scol;
  const ushort_t* Bsrc = B + (size_t)(bj * 256 + strow) * KK + scol;

  // fragment read map: row = base + m*16 + l15; phys slot = (kh*4+l4) ^ (l15&7)
  const int arow0 = wr * 128 + l15;
  const int brow0 = wc * 64 + l15;
  const int ap0 = ((l4) ^ (l15 & 7)) * 8;        // kh=0, elem offset within row
  const int ap1 = ((4 + l4) ^ (l15 & 7)) * 8;    // kh=1

  f32x4 acc[8][4] = {};

#define MFMA16(a, b, c) __builtin_amdgcn_mfma_f32_16x16x32_bf16(a, b, c, 0, 0, 0)

  // prologue: stage tile 0 into buf 0
#pragma unroll
  for (int i = 0; i < 4; ++i)
    glds16(Asrc + (size_t)i * 64 * KK, &AL[0][tid * 8 + i * 4096]);
#pragma unroll
  for (int i = 0; i < 4; ++i)
    glds16(Bsrc + (size_t)i * 64 * KK, &BL[0][tid * 8 + i * 4096]);
  __syncthreads();

  for (int t = 0; t < 16; ++t) {
    const int buf = t & 1, nxt = buf ^ 1;
    const size_t kk = (size_t)(t + 1) * 64;
    short8v af[8], b0, b1;

    // ---- phase 0: stage A(t+1); read A kh0 frags + B n0,n1 kh0; 16 MFMA ----
    if (t < 15) {
#pragma unroll
      for (int i = 0; i < 4; ++i)
        glds16(Asrc + (size_t)i * 64 * KK + kk, &AL[nxt][tid * 8 + i * 4096]);
    }
#pragma unroll
    for (int m = 0; m < 8; ++m)
      af[m] = *(const short8v*)&AL[buf][(arow0 + m * 16) * 64 + ap0];
    b0 = *(const short8v*)&BL[buf][(brow0) * 64 + ap0];
    b1 = *(const short8v*)&BL[buf][(brow0 + 16) * 64 + ap0];
    __builtin_amdgcn_s_setprio(1);
#pragma unroll
    for (int m = 0; m < 8; ++m) {
      acc[m][0] = MFMA16(af[m], b0, acc[m][0]);
      acc[m][1] = MFMA16(af[m], b1, acc[m][1]);
    }
    __builtin_amdgcn_s_setprio(0);

    // ---- phase 1: stage B(t+1); read B n2,n3 kh0; 16 MFMA (A regs reused) ---
    if (t < 15) {
#pragma unroll
      for (int i = 0; i < 4; ++i)
        glds16(Bsrc + (size_t)i * 64 * KK + kk, &BL[nxt][tid * 8 + i * 4096]);
    }
    b0 = *(const short8v*)&BL[buf][(brow0 + 32) * 64 + ap0];
    b1 = *(const short8v*)&BL[buf][(brow0 + 48) * 64 + ap0];
    __builtin_amdgcn_s_setprio(1);
#pragma unroll
    for (int m = 0; m < 8; ++m) {
      acc[m][2] = MFMA16(af[m], b0, acc[m][2]);
      acc[m][3] = MFMA16(af[m], b1, acc[m][3]);
    }
    __builtin_amdgcn_s_setprio(0);

    // ---- phase 2: read A kh1 frags + B n0,n1 kh1; 16 MFMA -------------------
#pragma unroll
    for (int m = 0; m < 8; ++m)
      af[m] = *(const short8v*)&AL[buf][(arow0 + m * 16) * 64 + ap1];
    b0 = *(const short8v*)&BL[buf][(brow0) * 64 + ap1];
    b1 = *(const short8v*)&BL[buf][(brow0 + 16) * 64 + ap1];
    __builtin_amdgcn_s_setprio(1);
#pragma unroll
    for (int m = 0; m < 8; ++m) {
      acc[m][0] = MFMA16(af[m], b0, acc[m][0]);
      acc[m][1] = MFMA16(af[m], b1, acc[m][1]);
    }
    __builtin_amdgcn_s_setprio(0);

    // ---- phase 3: read B n2,n3 kh1; 16 MFMA --------------------------------
    b0 = *(const short8v*)&BL[buf][(brow0 + 32) * 64 + ap1];
    b1 = *(const short8v*)&BL[buf][(brow0 + 48) * 64 + ap1];
    __builtin_amdgcn_s_setprio(1);
#pragma unroll
    for (int m = 0; m < 8; ++m) {
      acc[m][2] = MFMA16(af[m], b0, acc[m][2]);
      acc[m][3] = MFMA16(af[m], b1, acc[m][3]);
    }
    __builtin_amdgcn_s_setprio(0);

    __syncthreads();   // one barrier per K-tile; vmcnt drain covered by ~full tile
  }
#undef MFMA16

  // ---- epilogue: masked (strictly below anchor, off-diagonal) row/col max ----
  // C/D layout: col = lane&15, row = (lane>>4)*4 + reg
  const int rbase = bi * 256 + wr * 128;
  const int cbase = bj * 256 + wc * 64;

  float ar[32], ac[4];
#pragma unroll
  for (int m = 0; m < 8; ++m)
#pragma unroll
    for (int r = 0; r < 4; ++r)
      ar[m * 4 + r] = anchor[rbase + m * 16 + l4 * 4 + r];
#pragma unroll
  for (int n = 0; n < 4; ++n)
    ac[n] = anchor[cbase + n * 16 + l15];

  // row maxima: reduce over l15 (xor 1,2,4,8)
#pragma unroll
  for (int m = 0; m < 8; ++m) {
#pragma unroll
    for (int r = 0; r < 4; ++r) {
      const int rg = rbase + m * 16 + l4 * 4 + r;
      const float a = ar[m * 4 + r];
      uint32_t e = 0;
#pragma unroll
      for (int n = 0; n < 4; ++n) {
        const int cg = cbase + n * 16 + l15;
        float v = acc[m][n][r];
        if (v < a && rg != cg) { uint32_t fe = fenc(v); e = (fe > e) ? fe : e; }
      }
#pragma unroll
      for (int sh = 1; sh < 16; sh <<= 1) {
        uint32_t o = (uint32_t)__shfl_xor((int)e, sh, 64);
        e = (o > e) ? o : e;
      }
      if (l15 == 0 && e) atomicMax(&rowmax[rg], e);
    }
  }
  // col maxima: reduce over l4 (xor 16,32)
#pragma unroll
  for (int n = 0; n < 4; ++n) {
    const int cg = cbase + n * 16 + l15;
    const float a = ac[n];
    uint32_t e = 0;
#pragma unroll
    for (int m = 0; m < 8; ++m) {
#pragma unroll
      for (int r = 0; r < 4; ++r) {
        const int rg = rbase + m * 16 + l4 * 4 + r;
        float v = acc[m][n][r];
        if (v < a && rg != cg) { uint32_t fe = fenc(v); e = (fe > e) ? fe : e; }
      }
    }
    {
      uint32_t o = (uint32_t)__shfl_xor((int)e, 16, 64); e = (o > e) ? o : e;
      o = (uint32_t)__shfl_xor((int)e, 32, 64);          e = (o > e) ? o : e;
    }
    if (l4 == 0 && e) atomicMax(&colmax[cg], e);
  }
}

// ---------------- Kernel 4: hinge terms + mean -------------------------------
__global__ __launch_bounds__(256) void k_final(
    const float* __restrict__ anchor,
    const float* __restrict__ irr, const float* __restrict__ irf,
    const float* __restrict__ icr, const float* __restrict__ icf,
    const uint32_t* __restrict__ rowmax, const uint32_t* __restrict__ colmax,
    float* __restrict__ out) {
  float s = 0.f;
  for (int k = (int)threadIdx.x; k < NN; k += 256) {
    float a = anchor[k];
    float d1 = fmaxf(irr[k] - a + 1.0f, 0.f);
    uint32_t rm = rowmax[k];
    float imp2r = rm ? fdec(rm) : irf[k];
    float d2 = fmaxf(imp2r - a + 1.0f, 0.f);
    float e1 = fmaxf(icr[k] - a + 1.0f, 0.f);
    uint32_t cm = colmax[k];
    float imp2c = cm ? fdec(cm) : icf[k];
    float e2 = fmaxf(imp2c - a + 1.0f, 0.f);
    s += d1 + d2 + e1 + e2;
  }
  __shared__ float red[4];
  for (int m = 32; m >= 1; m >>= 1) s += __shfl_xor(s, m);
  if ((threadIdx.x & 63) == 0) red[threadIdx.x >> 6] = s;
  __syncthreads();
  if (threadIdx.x == 0) out[0] = (red[0] + red[1] + red[2] + red[3]) * (1.0f / NN);
}

// -----------------------------------------------------------------------------
extern "C" void kernel_launch(void* const* d_in, const int* in_sizes, int n_in,
                              void* d_out, int out_size, void* d_ws, size_t ws_size,
                              hipStream_t stream) {
  const float* X = (const float*)d_in[0];
  const float* Y = (const float*)d_in[1];
  float* out = (float*)d_out;

  char* ws = (char*)d_ws;
  float* anchor    = (float*)(ws + 0 * 16384);
  float* irr       = (float*)(ws + 1 * 16384);
  float* irf       = (float*)(ws + 2 * 16384);
  float* icr       = (float*)(ws + 3 * 16384);
  float* icf       = (float*)(ws + 4 * 16384);
  uint32_t* rowmax = (uint32_t*)(ws + 5 * 16384);
  uint32_t* colmax = (uint32_t*)(ws + 6 * 16384);
  ushort_t* Xb     = (ushort_t*)(ws + 256 * 1024);
  ushort_t* Yb     = Xb + (size_t)NN * KK;

  // subkeys = split(key(42), 4), partitionable: sk_i = threefry((0,42),(0,i))
  uint32_t sk[4][2];
  for (int i = 0; i < 4; ++i) tf2x32(0u, 42u, 0u, (uint32_t)i, &sk[i][0], &sk[i][1]);

  k_prep<<<4096, 256, 0, stream>>>((const float4*)X, (const float4*)Y,
                                   (ushort4*)Xb, (ushort4*)Yb, rowmax, colmax);

  k_dots<<<NN / 4, 256, 0, stream>>>(X, Y,
      sk[0][0], sk[0][1], sk[1][0], sk[1][1], sk[2][0], sk[2][1], sk[3][0], sk[3][1],
      anchor, irr, irf, icr, icf);

  k_gemm256<<<256, 512, 0, stream>>>(Xb, Yb, anchor, rowmax, colmax);

  k_final<<<1, 256, 0, stream>>>(anchor, irr, irf, icr, icf, rowmax, colmax, out);
}

// Round 5
// 94.769 us; speedup vs baseline: 5.2043x; 1.0539x over previous
//
#include <hip/hip_runtime.h>
#include <stdint.h>
#include <stddef.h>

#define NN 4096
#define KK 1024
#define SPAN 4095u

typedef unsigned short ushort_t;
typedef __attribute__((ext_vector_type(8))) short short8v;   // 8 bf16 = 4 VGPR
typedef __attribute__((ext_vector_type(4))) float f32x4;     // MFMA C/D

// ---------------- Threefry-2x32, 20 rounds (exact JAX algorithm) -------------
__host__ __device__ inline void tf2x32(uint32_t k0, uint32_t k1,
                                       uint32_t x0, uint32_t x1,
                                       uint32_t* o0, uint32_t* o1) {
  uint32_t ks2 = k0 ^ k1 ^ 0x1BD11BDAu;
  uint32_t v0 = x0 + k0;
  uint32_t v1 = x1 + k1;
#define TF_ROT(x, r) (((x) << (r)) | ((x) >> (32 - (r))))
#define TF_RND(r) do { v0 += v1; v1 = TF_ROT(v1, r); v1 ^= v0; } while (0)
  TF_RND(13); TF_RND(15); TF_RND(26); TF_RND(6);
  v0 += k1;  v1 += ks2 + 1u;
  TF_RND(17); TF_RND(29); TF_RND(16); TF_RND(24);
  v0 += ks2; v1 += k0 + 2u;
  TF_RND(13); TF_RND(15); TF_RND(26); TF_RND(6);
  v0 += k0;  v1 += k1 + 3u;
  TF_RND(17); TF_RND(29); TF_RND(16); TF_RND(24);
  v0 += k1;  v1 += ks2 + 4u;
  TF_RND(13); TF_RND(15); TF_RND(26); TF_RND(6);
  v0 += ks2; v1 += k0 + 5u;
#undef TF_RND
#undef TF_ROT
  *o0 = v0; *o1 = v1;
}

__device__ inline uint32_t rb32(uint32_t ka, uint32_t kb, uint32_t i) {
  uint32_t a, b;
  tf2x32(ka, kb, 0u, i, &a, &b);
  return a ^ b;
}

// Monotone order-preserving float<->uint32 encoding; 0 == "no candidate".
__device__ inline uint32_t fenc(float f) {
  uint32_t b = __float_as_uint(f);
  return (b & 0x80000000u) ? ~b : (b | 0x80000000u);
}
__device__ inline float fdec(uint32_t e) {
  uint32_t b = (e & 0x80000000u) ? (e & 0x7FFFFFFFu) : ~e;
  return __uint_as_float(b);
}

__device__ inline ushort_t bf16rne(float f) {   // fp32 -> bf16 round-nearest-even
  uint32_t u = __float_as_uint(f);
  return (ushort_t)((u + 0x7FFFu + ((u >> 16) & 1u)) >> 16);
}

__device__ inline void glds16(const void* g, void* l) {
  __builtin_amdgcn_global_load_lds((const __attribute__((address_space(1))) void*)g,
                                   (__attribute__((address_space(3))) void*)l, 16, 0, 0);
}

// ---------------- Kernel 1: fp32->bf16 convert for X,Y + zero max tables -----
__global__ __launch_bounds__(256) void k_prep(
    const float4* __restrict__ X, const float4* __restrict__ Y,
    ushort4* __restrict__ Xb, ushort4* __restrict__ Yb,
    uint32_t* __restrict__ rowmax, uint32_t* __restrict__ colmax) {
  const int b = blockIdx.x, tid = threadIdx.x;
  if (b < 16) rowmax[b * 256 + tid] = 0u;
  else if (b < 32) colmax[(b - 16) * 256 + tid] = 0u;
  const float4* src = (b < 2048) ? X : Y;
  ushort4* dst = (b < 2048) ? Xb : Yb;
  const int n4 = NN * KK / 4;
  for (int i = (b & 2047) * 256 + tid; i < n4; i += 2048 * 256) {
    float4 v = src[i];
    ushort4 o;
    o.x = bf16rne(v.x); o.y = bf16rne(v.y); o.z = bf16rne(v.z); o.w = bf16rne(v.w);
    dst[i] = o;
  }
}

// ---------------- Kernel 2: anchors + 4 gathered imposter dots (inline PRNG) -
__global__ __launch_bounds__(256) void k_dots(
    const float* __restrict__ X, const float* __restrict__ Y,
    uint32_t s0a, uint32_t s0b, uint32_t s1a, uint32_t s1b,
    uint32_t s2a, uint32_t s2b, uint32_t s3a, uint32_t s3b,
    float* __restrict__ anchor, float* __restrict__ irr, float* __restrict__ irf,
    float* __restrict__ icr, float* __restrict__ icf) {
  const int wid = threadIdx.x >> 6;
  const int lane = threadIdx.x & 63;
  const int row = blockIdx.x * 4 + wid;

  int jl = 0;
  if (lane < 4) {
    uint32_t ka = (lane == 0) ? s0a : (lane == 1) ? s1a : (lane == 2) ? s2a : s3a;
    uint32_t kb = (lane == 0) ? s0b : (lane == 1) ? s1b : (lane == 2) ? s2b : s3b;
    uint32_t k1a, k1b, k2a, k2b;
    tf2x32(ka, kb, 0u, 0u, &k1a, &k1b);
    tf2x32(ka, kb, 0u, 1u, &k2a, &k2b);
    uint32_t hi = rb32(k1a, k1b, (uint32_t)row);
    uint32_t lo = rb32(k2a, k2b, (uint32_t)row);
    uint32_t off = ((hi % SPAN) * 256u + (lo % SPAN)) % SPAN;
    int j = (int)off;
    jl = j + ((j >= row) ? 1 : 0);
  }
  const int j1r = __shfl(jl, 0), j1f = __shfl(jl, 1);
  const int j2r = __shfl(jl, 2), j2f = __shfl(jl, 3);

  const float4* xk = (const float4*)(X + (size_t)row * KK);
  const float4* yk = (const float4*)(Y + (size_t)row * KK);
  const float4* y1 = (const float4*)(Y + (size_t)j1r * KK);
  const float4* y2 = (const float4*)(Y + (size_t)j1f * KK);
  const float4* x1 = (const float4*)(X + (size_t)j2r * KK);
  const float4* x2 = (const float4*)(X + (size_t)j2f * KK);
  float sa = 0.f, s1 = 0.f, s2 = 0.f, s3 = 0.f, s4 = 0.f;
  for (int t = lane; t < KK / 4; t += 64) {
    float4 xv = xk[t], yv = yk[t], a1 = y1[t], a2 = y2[t], b1 = x1[t], b2 = x2[t];
    sa = fmaf(xv.x, yv.x, fmaf(xv.y, yv.y, fmaf(xv.z, yv.z, fmaf(xv.w, yv.w, sa))));
    s1 = fmaf(xv.x, a1.x, fmaf(xv.y, a1.y, fmaf(xv.z, a1.z, fmaf(xv.w, a1.w, s1))));
    s2 = fmaf(xv.x, a2.x, fmaf(xv.y, a2.y, fmaf(xv.z, a2.z, fmaf(xv.w, a2.w, s2))));
    s3 = fmaf(b1.x, yv.x, fmaf(b1.y, yv.y, fmaf(b1.z, yv.z, fmaf(b1.w, yv.w, s3))));
    s4 = fmaf(b2.x, yv.x, fmaf(b2.y, yv.y, fmaf(b2.z, yv.z, fmaf(b2.w, yv.w, s4))));
  }
  for (int m = 32; m >= 1; m >>= 1) {
    sa += __shfl_xor(sa, m);
    s1 += __shfl_xor(s1, m);
    s2 += __shfl_xor(s2, m);
    s3 += __shfl_xor(s3, m);
    s4 += __shfl_xor(s4, m);
  }
  if (lane == 0) {
    anchor[row] = sa; irr[row] = s1; irf[row] = s2; icr[row] = s3; icf[row] = s4;
  }
}

// ------------- Kernel 3: 256x256 MFMA GEMM, m201-style 8-phase schedule ------
// LDS: [dbuf 2][half 2][128 rows][64 k] bf16 for A and B = 128 KB total.
// Per iteration: 2 K-tiles (d=0: phases 1-4, d=1: phases 5-8), 16 MFMA/phase.
// Wave (wr,wc): A-half = wr, B-half = wc>>1 (each wave reads exactly one half).
// Phase reads: p1: A m0-3 (8) + B n0-1 (4); p2: B n2-3 (4); p3: A m4-7 (8);
// p4: none (B0 kept in regs). Staging (4x glds16): p3->B[d0], p4->A[d0] (tile
// t+2); p7->B[d1], p8->A[d1] (tile t+3) - each half staged one phase after its
// last LDS read (WAR-safe via the phase barriers). Counted waits: vmcnt(8) +
// barrier at p4/p8 ends only (8 = loads issued after the protected tile's
// staging; 4-phase issue->wait distance). Tail stages wrap (kt & 15) to keep
// vmcnt counts exact; wrapped data is overwritten-after-read, never consumed.
// 16B-slot XOR swizzle phys = log ^ (row & 7), applied on global source +
// ds_read address (rule #21); measured 0 bank conflicts (r4).

__global__ __launch_bounds__(512, 2) void k_gemm8p(
    const ushort_t* __restrict__ A, const ushort_t* __restrict__ B,
    const float* __restrict__ anchor,
    uint32_t* __restrict__ rowmax, uint32_t* __restrict__ colmax) {
  __shared__ ushort_t AL[2][2][8192];
  __shared__ ushort_t BL[2][2][8192];

  const int tid = threadIdx.x;
  const int lane = tid & 63;
  const int w = tid >> 6, wr = w >> 2, wc = w & 3;   // 8 waves: 2M x 4N
  const int l15 = lane & 15, l4 = lane >> 4;

  // T1: XCD-aware bijective swizzle (256 blocks % 8 == 0)
  const int swz = (blockIdx.x & 7) * 32 + (blockIdx.x >> 3);
  const int bi = swz >> 4, bj = swz & 15;

  // staging: per half-tile 2 glds/thread; row = tid>>3 (+64), phys slot = tid&7
  const int strow = tid >> 3;
  const int scol = ((tid & 7) ^ (strow & 7)) * 8;
  const ushort_t* Abase = A + (size_t)(bi * 256 + strow) * KK + scol;
  const ushort_t* Bbase = B + (size_t)(bj * 256 + strow) * KK + scol;

  // ds_read slot select (element offset within 64-elem row) per kh
  const int ss0 = ((0 * 4 + l4) ^ (l15 & 7)) * 8;
  const int ss1 = ((1 * 4 + l4) ^ (l15 & 7)) * 8;
  const int bhalf = wc >> 1, brow0 = (wc & 1) * 64 + l15;

  f32x4 acc[8][4] = {};
  short8v Areg[4][2], B0r[2][2], B1r[2][2];

#define STAGE_A(DD, KT)                                                        \
  do {                                                                         \
    glds16(Abase + (size_t)0 * KK + (KT) * 64,   &AL[DD][0][tid * 8]);         \
    glds16(Abase + (size_t)64 * KK + (KT) * 64,  &AL[DD][0][4096 + tid * 8]);  \
    glds16(Abase + (size_t)128 * KK + (KT) * 64, &AL[DD][1][tid * 8]);         \
    glds16(Abase + (size_t)192 * KK + (KT) * 64, &AL[DD][1][4096 + tid * 8]);  \
  } while (0)
#define STAGE_B(DD, KT)                                                        \
  do {                                                                         \
    glds16(Bbase + (size_t)0 * KK + (KT) * 64,   &BL[DD][0][tid * 8]);         \
    glds16(Bbase + (size_t)64 * KK + (KT) * 64,  &BL[DD][0][4096 + tid * 8]);  \
    glds16(Bbase + (size_t)128 * KK + (KT) * 64, &BL[DD][1][tid * 8]);         \
    glds16(Bbase + (size_t)192 * KK + (KT) * 64, &BL[DD][1][4096 + tid * 8]);  \
  } while (0)

#define BAR() do { __builtin_amdgcn_s_barrier(); \
                   __builtin_amdgcn_sched_barrier(0); } while (0)
#define LGKM0() do { asm volatile("s_waitcnt lgkmcnt(0)" ::: "memory"); \
                     __builtin_amdgcn_sched_barrier(0); } while (0)
#define VM8BAR() do { asm volatile("s_waitcnt vmcnt(8)" ::: "memory"); \
                      __builtin_amdgcn_s_barrier(); \
                      __builtin_amdgcn_sched_barrier(0); } while (0)

#define MFMA1(a, b, c) c = __builtin_amdgcn_mfma_f32_16x16x32_bf16(a, b, c, 0, 0, 0)
  // 16 MFMA cluster: m-sub MS (rows MS*4..MS*4+3), B-frag pair BR -> n cols NS*2,NS*2+1
#define CL16(MS, NS, BR)                                                       \
  do {                                                                         \
    __builtin_amdgcn_s_setprio(1);                                             \
    _Pragma("unroll")                                                          \
    for (int q = 0; q < 4; ++q) {                                              \
      MFMA1(Areg[q][0], BR[0][0], acc[(MS) * 4 + q][(NS) * 2]);                \
      MFMA1(Areg[q][0], BR[1][0], acc[(MS) * 4 + q][(NS) * 2 + 1]);            \
      MFMA1(Areg[q][1], BR[0][1], acc[(MS) * 4 + q][(NS) * 2]);                \
      MFMA1(Areg[q][1], BR[1][1], acc[(MS) * 4 + q][(NS) * 2 + 1]);            \
    }                                                                          \
    __builtin_amdgcn_s_setprio(0);                                             \
  } while (0)

#define LDA(D, M, KH) (*(const short8v*)&AL[D][wr][((M) * 16 + l15) * 64 + ((KH) ? ss1 : ss0)])
#define LDB(D, N, KH) (*(const short8v*)&BL[D][bhalf][(brow0 + (N) * 16) * 64 + ((KH) ? ss1 : ss0)])

  // prologue: stage tiles 0 (d0) and 1 (d1); wait for d0's 8 loads
  STAGE_B(0, 0); STAGE_A(0, 0);
  STAGE_B(1, 1); STAGE_A(1, 1);
  asm volatile("s_waitcnt vmcnt(8)" ::: "memory");
  __builtin_amdgcn_s_barrier();
  __builtin_amdgcn_sched_barrier(0);

  for (int i = 0; i < 8; ++i) {
    const int kt2 = (2 * i + 2) & 15, kt3 = (2 * i + 3) & 15;

    // ---------------- phases 1-4: compute K-tile 2i from d0 -----------------
    // p1: read A m0-3 + B n0-1; MFMA (m0-3 x n0-1)
#pragma unroll
    for (int q = 0; q < 4; ++q) { Areg[q][0] = LDA(0, q, 0); Areg[q][1] = LDA(0, q, 1); }
#pragma unroll
    for (int n = 0; n < 2; ++n) { B0r[n][0] = LDB(0, n, 0); B0r[n][1] = LDB(0, n, 1); }
    BAR(); LGKM0();
    CL16(0, 0, B0r);
    BAR();

    // p2: read B n2-3; MFMA (m0-3 x n2-3)
#pragma unroll
    for (int n = 0; n < 2; ++n) { B1r[n][0] = LDB(0, n + 2, 0); B1r[n][1] = LDB(0, n + 2, 1); }
    BAR(); LGKM0();
    CL16(0, 1, B1r);
    BAR();

    // p3: read A m4-7; stage B[d0] <- tile kt2; MFMA (m4-7 x n2-3)
#pragma unroll
    for (int q = 0; q < 4; ++q) { Areg[q][0] = LDA(0, q + 4, 0); Areg[q][1] = LDA(0, q + 4, 1); }
    STAGE_B(0, kt2);
    BAR(); LGKM0();
    CL16(1, 1, B1r);
    BAR();

    // p4: stage A[d0] <- tile kt2; MFMA (m4-7 x n0-1, B0 from regs); vmcnt(8)
    STAGE_A(0, kt2);
    BAR(); LGKM0();
    CL16(1, 0, B0r);
    VM8BAR();

    // ---------------- phases 5-8: compute K-tile 2i+1 from d1 ---------------
    // p5
#pragma unroll
    for (int q = 0; q < 4; ++q) { Areg[q][0] = LDA(1, q, 0); Areg[q][1] = LDA(1, q, 1); }
#pragma unroll
    for (int n = 0; n < 2; ++n) { B0r[n][0] = LDB(1, n, 0); B0r[n][1] = LDB(1, n, 1); }
    BAR(); LGKM0();
    CL16(0, 0, B0r);
    BAR();

    // p6
#pragma unroll
    for (int n = 0; n < 2; ++n) { B1r[n][0] = LDB(1, n + 2, 0); B1r[n][1] = LDB(1, n + 2, 1); }
    BAR(); LGKM0();
    CL16(0, 1, B1r);
    BAR();

    // p7
#pragma unroll
    for (int q = 0; q < 4; ++q) { Areg[q][0] = LDA(1, q + 4, 0); Areg[q][1] = LDA(1, q + 4, 1); }
    STAGE_B(1, kt3);
    BAR(); LGKM0();
    CL16(1, 1, B1r);
    BAR();

    // p8
    STAGE_A(1, kt3);
    BAR(); LGKM0();
    CL16(1, 0, B0r);
    VM8BAR();
  }

#undef LDA
#undef LDB
#undef CL16
#undef MFMA1
#undef VM8BAR
#undef LGKM0
#undef BAR
#undef STAGE_A
#undef STAGE_B

  // ---- epilogue: masked (strictly below anchor, off-diagonal) row/col max ----
  // C/D layout: col = lane&15, row = (lane>>4)*4 + reg
  const int rbase = bi * 256 + wr * 128;
  const int cbase = bj * 256 + wc * 64;

  float ar[32], ac[4];
#pragma unroll
  for (int m = 0; m < 8; ++m)
#pragma unroll
    for (int r = 0; r < 4; ++r)
      ar[m * 4 + r] = anchor[rbase + m * 16 + l4 * 4 + r];
#pragma unroll
  for (int n = 0; n < 4; ++n)
    ac[n] = anchor[cbase + n * 16 + l15];

  // row maxima: reduce over l15 (xor 1,2,4,8)
#pragma unroll
  for (int m = 0; m < 8; ++m) {
#pragma unroll
    for (int r = 0; r < 4; ++r) {
      const int rg = rbase + m * 16 + l4 * 4 + r;
      const float a = ar[m * 4 + r];
      uint32_t e = 0;
#pragma unroll
      for (int n = 0; n < 4; ++n) {
        const int cg = cbase + n * 16 + l15;
        float v = acc[m][n][r];
        if (v < a && rg != cg) { uint32_t fe = fenc(v); e = (fe > e) ? fe : e; }
      }
#pragma unroll
      for (int sh = 1; sh < 16; sh <<= 1) {
        uint32_t o = (uint32_t)__shfl_xor((int)e, sh, 64);
        e = (o > e) ? o : e;
      }
      if (l15 == 0 && e) atomicMax(&rowmax[rg], e);
    }
  }
  // col maxima: reduce over l4 (xor 16,32)
#pragma unroll
  for (int n = 0; n < 4; ++n) {
    const int cg = cbase + n * 16 + l15;
    const float a = ac[n];
    uint32_t e = 0;
#pragma unroll
    for (int m = 0; m < 8; ++m) {
#pragma unroll
      for (int r = 0; r < 4; ++r) {
        const int rg = rbase + m * 16 + l4 * 4 + r;
        float v = acc[m][n][r];
        if (v < a && rg != cg) { uint32_t fe = fenc(v); e = (fe > e) ? fe : e; }
      }
    }
    {
      uint32_t o = (uint32_t)__shfl_xor((int)e, 16, 64); e = (o > e) ? o : e;
      o = (uint32_t)__shfl_xor((int)e, 32, 64);          e = (o > e) ? o : e;
    }
    if (l4 == 0 && e) atomicMax(&colmax[cg], e);
  }
}

// ---------------- Kernel 4: hinge terms + mean -------------------------------
__global__ __launch_bounds__(256) void k_final(
    const float* __restrict__ anchor,
    const float* __restrict__ irr, const float* __restrict__ irf,
    const float* __restrict__ icr, const float* __restrict__ icf,
    const uint32_t* __restrict__ rowmax, const uint32_t* __restrict__ colmax,
    float* __restrict__ out) {
  float s = 0.f;
  for (int k = (int)threadIdx.x; k < NN; k += 256) {
    float a = anchor[k];
    float d1 = fmaxf(irr[k] - a + 1.0f, 0.f);
    uint32_t rm = rowmax[k];
    float imp2r = rm ? fdec(rm) : irf[k];
    float d2 = fmaxf(imp2r - a + 1.0f, 0.f);
    float e1 = fmaxf(icr[k] - a + 1.0f, 0.f);
    uint32_t cm = colmax[k];
    float imp2c = cm ? fdec(cm) : icf[k];
    float e2 = fmaxf(imp2c - a + 1.0f, 0.f);
    s += d1 + d2 + e1 + e2;
  }
  __shared__ float red[4];
  for (int m = 32; m >= 1; m >>= 1) s += __shfl_xor(s, m);
  if ((threadIdx.x & 63) == 0) red[threadIdx.x >> 6] = s;
  __syncthreads();
  if (threadIdx.x == 0) out[0] = (red[0] + red[1] + red[2] + red[3]) * (1.0f / NN);
}

// -----------------------------------------------------------------------------
extern "C" void kernel_launch(void* const* d_in, const int* in_sizes, int n_in,
                              void* d_out, int out_size, void* d_ws, size_t ws_size,
                              hipStream_t stream) {
  const float* X = (const float*)d_in[0];
  const float* Y = (const float*)d_in[1];
  float* out = (float*)d_out;

  char* ws = (char*)d_ws;
  float* anchor    = (float*)(ws + 0 * 16384);
  float* irr       = (float*)(ws + 1 * 16384);
  float* irf       = (float*)(ws + 2 * 16384);
  float* icr       = (float*)(ws + 3 * 16384);
  float* icf       = (float*)(ws + 4 * 16384);
  uint32_t* rowmax = (uint32_t*)(ws + 5 * 16384);
  uint32_t* colmax = (uint32_t*)(ws + 6 * 16384);
  ushort_t* Xb     = (ushort_t*)(ws + 256 * 1024);
  ushort_t* Yb     = Xb + (size_t)NN * KK;

  // subkeys = split(key(42), 4), partitionable: sk_i = threefry((0,42),(0,i))
  uint32_t sk[4][2];
  for (int i = 0; i < 4; ++i) tf2x32(0u, 42u, 0u, (uint32_t)i, &sk[i][0], &sk[i][1]);

  k_prep<<<4096, 256, 0, stream>>>((const float4*)X, (const float4*)Y,
                                   (ushort4*)Xb, (ushort4*)Yb, rowmax, colmax);

  k_dots<<<NN / 4, 256, 0, stream>>>(X, Y,
      sk[0][0], sk[0][1], sk[1][0], sk[1][1], sk[2][0], sk[2][1], sk[3][0], sk[3][1],
      anchor, irr, irf, icr, icf);

  k_gemm8p<<<256, 512, 0, stream>>>(Xb, Yb, anchor, rowmax, colmax);

  k_final<<<1, 256, 0, stream>>>(anchor, irr, irf, icr, icf, rowmax, colmax, out);
}